// Round 10
// baseline (48.627 us; speedup 1.0000x reference)
//
#include <hip/hip_runtime.h>

#define D_FEAT  128
#define NBLK    256    // fused-kernel grid: <= CU count -> guaranteed co-resident
#define EPT     13     // 256 blk * 256 thr * 13 = 851968 >= 800000 edges

// K1: per-node projection, 8-lane group per node (32 nodes / 256-thread block).
// pu[n] = h[n].Wu + b ; pv[n] = h[n].Wv. Block 0 also zero-inits the sync cells
// (visible to K2 via the dispatch boundary).
__global__ __launch_bounds__(256) void proj_kernel(
    const float* __restrict__ h,
    const float* __restrict__ W,
    const float* __restrict__ bptr,
    float* __restrict__ pu,
    float* __restrict__ pv,
    unsigned* __restrict__ syncc,   // [0]=counter, [1]=flag
    int n_nodes)
{
    if (blockIdx.x == 0 && threadIdx.x == 0) { syncc[0] = 0u; syncc[1] = 0u; }

    const int t    = threadIdx.x & 7;
    const int node = blockIdx.x * 32 + (threadIdx.x >> 3);
    if (node >= n_nodes) return;

    const float4* W4 = (const float4*)W;
    float4 wu[4], wv[4];
    #pragma unroll
    for (int j = 0; j < 4; ++j) {
        wu[j] = W4[j * 8 + t];          // L1-resident after first wave
        wv[j] = W4[32 + j * 8 + t];
    }

    const float4* h4 = (const float4*)(h + (size_t)node * D_FEAT);
    float4 hv[4];
    #pragma unroll
    for (int j = 0; j < 4; ++j) hv[j] = h4[j * 8 + t];   // 64 B/lane in flight

    float su = 0.f, sv = 0.f;
    #pragma unroll
    for (int j = 0; j < 4; ++j) {
        su += hv[j].x*wu[j].x + hv[j].y*wu[j].y + hv[j].z*wu[j].z + hv[j].w*wu[j].w;
        sv += hv[j].x*wv[j].x + hv[j].y*wv[j].y + hv[j].z*wv[j].z + hv[j].w*wv[j].w;
    }
    #pragma unroll
    for (int off = 4; off > 0; off >>= 1) {   // xor 4,2,1: stays in 8-lane group
        su += __shfl_xor(su, off, 64);
        sv += __shfl_xor(sv, off, 64);
    }
    if (t == 0) {
        pu[node] = su + bptr[0];   // bias folded in: score = pu[src]+pv[dst]
        pv[node] = sv;
    }
}

// K2 fused: scores in registers -> per-block partial (distinct-slot atomicExch)
// -> single-shot last-block barrier -> normalize from registers -> one write.
__global__ __launch_bounds__(256) void fused_score_norm_kernel(
    const int*   __restrict__ src,
    const int*   __restrict__ dst,
    const float* __restrict__ pu,
    const float* __restrict__ pv,
    float*       __restrict__ out,
    unsigned long long* __restrict__ partials,  // [NBLK], packed (max<<32|min)
    unsigned long long* __restrict__ gcell,     // packed (inv<<32|min)
    unsigned* __restrict__ syncc,               // [0]=counter, [1]=flag
    int n_edges)
{
    const int tid    = blockIdx.x * 256 + threadIdx.x;
    const int stride = NBLK * 256;

    // ---- phase A: up to EPT scores per thread, kept in registers ----
    float sc[EPT];
    float vmin =  3.4028235e38f;
    float vmax = -3.4028235e38f;
    #pragma unroll
    for (int k = 0; k < EPT; ++k) {
        const int e = tid + k * stride;
        float s = 0.f;
        if (e < n_edges) {
            s = pu[src[e]] + pv[dst[e]];   // pu/pv: 800 KB, L2/L3-resident
            vmin = fminf(vmin, s);
            vmax = fmaxf(vmax, s);
        }
        sc[k] = s;
    }
    #pragma unroll
    for (int off = 32; off > 0; off >>= 1) {
        vmin = fminf(vmin, __shfl_xor(vmin, off, 64));
        vmax = fmaxf(vmax, __shfl_xor(vmax, off, 64));
    }
    __shared__ float smin[4], smax[4];
    __shared__ int   isred;
    __shared__ unsigned g_lo, g_hi;
    const int w = threadIdx.x >> 6;
    if ((threadIdx.x & 63) == 0) { smin[w] = vmin; smax[w] = vmax; }
    __syncthreads();

    // ---- publish partial (device-scope, DISTINCT slot) + arrive at barrier ----
    if (threadIdx.x == 0) {
        const float a = fminf(fminf(smin[0], smin[1]), fminf(smin[2], smin[3]));
        const float m = fmaxf(fmaxf(smax[0], smax[1]), fmaxf(smax[2], smax[3]));
        const unsigned long long p =
            ((unsigned long long)__float_as_uint(m) << 32) | __float_as_uint(a);
        __hip_atomic_exchange(&partials[blockIdx.x], p,
                              __ATOMIC_RELEASE, __HIP_MEMORY_SCOPE_AGENT);
        const unsigned old = __hip_atomic_fetch_add(&syncc[0], 1u,
                              __ATOMIC_ACQ_REL, __HIP_MEMORY_SCOPE_AGENT);
        isred = (old == NBLK - 1);      // last arrival becomes the reducer
    }
    __syncthreads();

    if (isred) {
        // ---- reducer block: fold 256 partials, publish g, release flag ----
        const unsigned long long p = __hip_atomic_load(&partials[threadIdx.x],
                              __ATOMIC_ACQUIRE, __HIP_MEMORY_SCOPE_AGENT);
        float a = __uint_as_float((unsigned)(p & 0xFFFFFFFFull));
        float m = __uint_as_float((unsigned)(p >> 32));
        #pragma unroll
        for (int off = 32; off > 0; off >>= 1) {
            a = fminf(a, __shfl_xor(a, off, 64));
            m = fmaxf(m, __shfl_xor(m, off, 64));
        }
        if ((threadIdx.x & 63) == 0) { smin[w] = a; smax[w] = m; }
        __syncthreads();
        if (threadIdx.x == 0) {
            const float mn  = fminf(fminf(smin[0], smin[1]), fminf(smin[2], smin[3]));
            const float mx  = fmaxf(fmaxf(smax[0], smax[1]), fmaxf(smax[2], smax[3]));
            const float inv = 1.0f / (mx - mn);
            const unsigned long long gv =
                ((unsigned long long)__float_as_uint(inv) << 32) | __float_as_uint(mn);
            __hip_atomic_exchange(gcell, gv,
                                  __ATOMIC_RELEASE, __HIP_MEMORY_SCOPE_AGENT);
            __hip_atomic_store(&syncc[1], 1u,
                               __ATOMIC_RELEASE, __HIP_MEMORY_SCOPE_AGENT);
        }
        __syncthreads();
    } else {
        // ---- other blocks: one lane spins gently; no fences in the loop ----
        if (threadIdx.x == 0) {
            while (__hip_atomic_load(&syncc[1], __ATOMIC_RELAXED,
                                     __HIP_MEMORY_SCOPE_AGENT) == 0u)
                __builtin_amdgcn_s_sleep(2);
            (void)__hip_atomic_load(&syncc[1], __ATOMIC_ACQUIRE,
                                    __HIP_MEMORY_SCOPE_AGENT);
        }
        __syncthreads();
    }

    // ---- broadcast g via LDS, normalize registers, single coalesced write ----
    if (threadIdx.x == 0) {
        const unsigned long long gv = __hip_atomic_load(gcell,
                              __ATOMIC_ACQUIRE, __HIP_MEMORY_SCOPE_AGENT);
        g_lo = (unsigned)(gv & 0xFFFFFFFFull);
        g_hi = (unsigned)(gv >> 32);
    }
    __syncthreads();
    const float mn  = __uint_as_float(g_lo);
    const float inv = __uint_as_float(g_hi);
    #pragma unroll
    for (int k = 0; k < EPT; ++k) {
        const int e = tid + k * stride;
        if (e < n_edges) out[e] = (sc[k] - mn) * inv;
    }
}

extern "C" void kernel_launch(void* const* d_in, const int* in_sizes, int n_in,
                              void* d_out, int out_size, void* d_ws, size_t ws_size,
                              hipStream_t stream) {
    const float* h   = (const float*)d_in[0];
    const int*   src = (const int*)d_in[1];
    const int*   dst = (const int*)d_in[2];
    const float* W   = (const float*)d_in[3];
    const float* b   = (const float*)d_in[4];
    float* out = (float*)d_out;

    const int n_nodes = in_sizes[0] / D_FEAT;
    const int n_edges = in_sizes[1];

    // ws layout (8*n_nodes bytes are 8-aligned):
    //   pu[n_nodes] | pv[n_nodes] | partials[NBLK] (ull) | gcell (ull) | syncc[2]
    float* ws = (float*)d_ws;
    float* pu = ws;
    float* pv = ws + n_nodes;
    unsigned long long* partials = (unsigned long long*)(ws + 2 * n_nodes);
    unsigned long long* gcell    = partials + NBLK;
    unsigned*           syncc    = (unsigned*)(gcell + 1);

    // K1: 32 nodes / block -> 3125 blocks (also inits syncc)
    {
        const int blocks = (n_nodes + 31) / 32;
        proj_kernel<<<blocks, 256, 0, stream>>>(h, W, b, pu, pv, syncc, n_nodes);
    }
    // K2: fused score + global min/max + normalize, 256 co-resident blocks
    fused_score_norm_kernel<<<NBLK, 256, 0, stream>>>(
        src, dst, pu, pv, out, partials, gcell, syncc, n_edges);
}